// Round 6
// baseline (8235.743 us; speedup 1.0000x reference)
//
#include <hip/hip_runtime.h>

typedef unsigned short u16;
typedef unsigned int u32;
typedef unsigned long long u64;
typedef float f32x4 __attribute__((ext_vector_type(4)));
typedef __bf16 bf16x8 __attribute__((ext_vector_type(8)));
typedef u16 u16x8 __attribute__((ext_vector_type(8)));

#define T_STEPS 512
#define BATCH 64
#define HDIM 1024
#define GDIM 4096            // 4*H
#define HS_ELEMS (33554432u) // 512*64*1024
#define XP_STEP 262144       // u16 per t: 64 blk * 4 gate * 1024

__device__ __forceinline__ u16 f2bf(float f) {
  union { float f; u32 u; } v; v.f = f;
  u32 r = v.u + 0x7fffu + ((v.u >> 16) & 1u);
  return (u16)(r >> 16);
}
__device__ __forceinline__ float bf2f(u16 b) {
  union { u32 u; float f; } v; v.u = ((u32)b) << 16;
  return v.f;
}
__device__ __forceinline__ float sigm(float x) { return 1.f / (1.f + __expf(-x)); }
__device__ __forceinline__ float tanh_fast(float x) { return 1.f - 2.f / (__expf(2.f * x) + 1.f); }

// ---------------------------------------------------------------------------
// Kernel 1: transpose+convert W_x, W_h: [1024][4096] fp32 -> [4096][1024] bf16.
// ---------------------------------------------------------------------------
__global__ void transpose_w(const float* __restrict__ Wx, const float* __restrict__ Wh,
                            u16* __restrict__ WxT, u16* __restrict__ WhT) {
  __shared__ float tile[32][33];
  const float* src = blockIdx.z ? Wh : Wx;
  u16* dst = blockIdx.z ? WhT : WxT;
  const int n0 = blockIdx.x * 32, k0 = blockIdx.y * 32;
  const int tx = threadIdx.x, ty = threadIdx.y;
#pragma unroll
  for (int i = 0; i < 4; ++i)
    tile[ty + i * 8][tx] = src[(size_t)(k0 + ty + i * 8) * GDIM + n0 + tx];
  __syncthreads();
#pragma unroll
  for (int i = 0; i < 4; ++i)
    dst[(size_t)(n0 + ty + i * 8) * HDIM + k0 + tx] = f2bf(tile[tx][ty + i * 8]);
}

// ---------------------------------------------------------------------------
// Kernel 2: Xp = bf16(X @ W_x + b), blocked for the 64-block recurrence:
//   Xp[t][blk=bg*16+cr][gate][b_el*64+hcol]  (u16)
// ---------------------------------------------------------------------------
__global__ __launch_bounds__(256, 2) void gemm_xp(
    const float* __restrict__ X, const u16* __restrict__ WxT,
    const float* __restrict__ bias, u16* __restrict__ Xp) {
  __shared__ u16 As[128 * 40];
  __shared__ u16 Bs[128 * 40];
  const int tid = threadIdx.x;
  const int lane = tid & 63, w = tid >> 6;
  const int rl = lane & 15, gq = lane >> 4, g8 = gq * 8;
  const int swz = (blockIdx.x & 7) * 1024 + (blockIdx.x >> 3);
  const int m0 = (swz >> 5) * 128, n0 = (swz & 31) * 128;
  const int srow = tid >> 1, sseg = (tid & 1) * 16;
  const int rbase = (w >> 1) * 64, cbase = (w & 1) * 64;

  f32x4 acc[4][4] = {};
  for (int k0 = 0; k0 < 1024; k0 += 32) {
    const float4* ap = (const float4*)&X[(size_t)(m0 + srow) * 1024 + k0 + sseg];
    float4 v0 = ap[0], v1 = ap[1], v2 = ap[2], v3 = ap[3];
    u16x8 pa, pb;
    pa[0] = f2bf(v0.x); pa[1] = f2bf(v0.y); pa[2] = f2bf(v0.z); pa[3] = f2bf(v0.w);
    pa[4] = f2bf(v1.x); pa[5] = f2bf(v1.y); pa[6] = f2bf(v1.z); pa[7] = f2bf(v1.w);
    pb[0] = f2bf(v2.x); pb[1] = f2bf(v2.y); pb[2] = f2bf(v2.z); pb[3] = f2bf(v2.w);
    pb[4] = f2bf(v3.x); pb[5] = f2bf(v3.y); pb[6] = f2bf(v3.z); pb[7] = f2bf(v3.w);
    const u16x8* bp = (const u16x8*)&WxT[(size_t)(n0 + srow) * 1024 + k0 + sseg];
    u16x8 qa = bp[0], qb = bp[1];
    *(u16x8*)&As[srow * 40 + sseg] = pa;
    *(u16x8*)&As[srow * 40 + sseg + 8] = pb;
    *(u16x8*)&Bs[srow * 40 + sseg] = qa;
    *(u16x8*)&Bs[srow * 40 + sseg + 8] = qb;
    __syncthreads();
    bf16x8 av[4], bv[4];
#pragma unroll
    for (int i = 0; i < 4; ++i)
      av[i] = *(const bf16x8*)&As[(rbase + i * 16 + rl) * 40 + g8];
#pragma unroll
    for (int j = 0; j < 4; ++j)
      bv[j] = *(const bf16x8*)&Bs[(cbase + j * 16 + rl) * 40 + g8];
#pragma unroll
    for (int i = 0; i < 4; ++i)
#pragma unroll
      for (int j = 0; j < 4; ++j)
        acc[i][j] = __builtin_amdgcn_mfma_f32_16x16x32_bf16(av[i], bv[j], acc[i][j], 0, 0, 0);
    __syncthreads();
  }
#pragma unroll
  for (int j = 0; j < 4; ++j) {
    const int n = n0 + cbase + j * 16 + rl;
    const float bj = bias[n];
    const int gate = n >> 10, col = n & 1023;
    const int cr = col >> 6, hcol = col & 63;
#pragma unroll
    for (int i = 0; i < 4; ++i)
#pragma unroll
      for (int r = 0; r < 4; ++r) {
        const int m = m0 + rbase + i * 16 + gq * 4 + r;
        const int tt = m >> 6, b = m & 63;
        Xp[(size_t)tt * XP_STEP + (size_t)(((b >> 4) * 16 + cr) * 4) * 1024 +
           gate * 1024 + (b & 15) * 64 + hcol] = f2bf(acc[i][j][r] + bj);
      }
  }
}

// ---------------------------------------------------------------------------
// Kernel 3: zero h_tag (2 slots x 64 x 1024 u32 = 512KB), every launch
// (replay safety; h_tag aliases the dead WxT region).
// ---------------------------------------------------------------------------
__global__ void zero_tags(u32* __restrict__ ht) {
  ht[(size_t)blockIdx.x * 256 + threadIdx.x] = 0;
}

// ---------------------------------------------------------------------------
// Kernel 4: recurrence. Flagless tagged dataflow, 64 fat blocks.
// 64 blocks (1 per CU) = 4 bg-groups x 16 col-ranges; 1024 threads = 16 waves.
// Block (bg, cr) owns batches [bg*16..+16) x h-cols [cr*64..+64).
// Wave w: gate g=w>>2, col-quarter c4=w&3 -> 16x16 output tile, wf in VGPRs.
// Per-thread poll width: 8 u64 (vs 32 in R5) -> unpack VALU / 4.
// h fan-out: 16 consumers read 4MB/step aggregate (vs 16MB) -> less LLC
// congestion / HBM spill.
// Protocol (unchanged, proven): h word = (tag=t+1)<<16 | bf16; producers
// fire-and-forget relaxed agent stores; consumers poll tags in batched
// predicated rounds; 2-slot ping-pong safe by induction.
// ---------------------------------------------------------------------------
__global__ __launch_bounds__(1024, 1) void lstm_rec(
    const u16* __restrict__ Xp, const u16* __restrict__ WhT,
    u32* __restrict__ h_tag, float* __restrict__ out) {
  __shared__ u16 h_lds[16 * 1024]; // [16 rows][1024 k] bf16, XOR-swizzled
  __shared__ float gate_lds[4][4][16][20];
  const int tid = threadIdx.x;
  const int lane = tid & 63, w = tid >> 6;
  const int rl = lane & 15, gq = lane >> 4;
  const int cr = blockIdx.x & 15, bg = blockIdx.x >> 4;
  const int g = w >> 2, c4 = w & 3;

  // W_h fragments (wave (g,c4): cols g*1024 + cr*64 + c4*16 + rl)
  bf16x8 wf[32];
  {
    const size_t gcol = (size_t)(g * 1024 + cr * 64 + c4 * 16 + rl) * HDIM + gq * 8;
#pragma unroll
    for (int kk = 0; kk < 32; ++kk)
      wf[kk] = *(const bf16x8*)&WhT[gcol + kk * 32];
  }

  // elementwise/store ownership: thread -> (b_el, hcol)
  const int b_el = tid >> 6, hcol = tid & 63;
  // staging ownership: wave w covers LDS row w (srow==w), sseg = lane
  const int srow = w, sseg = lane;
  const int swz_w = ((srow & 7) << 4) ^ ((srow & 1) << 6);
  const int swz_r = ((rl & 7) << 4) ^ ((rl & 1) << 6);
  float creg = 0.f, hreg = 0.f;

  const u16* xp_p = Xp + (size_t)blockIdx.x * 4096 + tid;
  float xg0 = bf2f(xp_p[0]), xg1 = bf2f(xp_p[1024]),
        xg2 = bf2f(xp_p[2048]), xg3 = bf2f(xp_p[3072]);

  for (int t = 0; t < T_STEPS; ++t) {
    // prefetch next step's Xp (independent of h; overlaps poll latency)
    u16 nx0 = 0, nx1 = 0, nx2 = 0, nx3 = 0;
    if (t + 1 < T_STEPS) {
      const u16* p = xp_p + XP_STEP;
      nx0 = p[0]; nx1 = p[1024]; nx2 = p[2048]; nx3 = p[3072];
    }

    f32x4 acc0 = {0.f, 0.f, 0.f, 0.f}, acc1 = {0.f, 0.f, 0.f, 0.f};
    if (t > 0) {
      // batched tag-poll + stage: thread covers row srow, u64 words sseg+64u
      const u64* hrow =
          (const u64*)(h_tag + (size_t)(t & 1) * 65536 + (size_t)(bg * 16 + srow) * 1024);
      char* ldsrow = (char*)h_lds + srow * 2048;
      u64 v[8];
      u32 pend = 0xffu;
      while (pend) {
#pragma unroll
        for (int u = 0; u < 8; ++u)
          if (pend & (1u << u))
            v[u] = __hip_atomic_load(&hrow[sseg + 64 * u], __ATOMIC_RELAXED,
                                     __HIP_MEMORY_SCOPE_AGENT);
        u32 got = 0u;
#pragma unroll
        for (int u = 0; u < 8; ++u)
          if (pend & (1u << u)) {
            const u32 t0 = (u32)(v[u] >> 16) & 0xffffu, t1 = (u32)(v[u] >> 48);
            if (t0 >= (u32)t && t1 >= (u32)t) {
              const u32 pack = ((u32)v[u] & 0xffffu) | (((u32)(v[u] >> 32) & 0xffffu) << 16);
              *(u32*)(ldsrow + (((sseg + 64 * u) * 4) ^ swz_w)) = pack;
              got |= (1u << u);
            }
          }
        pend &= ~got;
      }
      __syncthreads();
      const char* hrd = (const char*)h_lds + rl * 2048;
#pragma unroll
      for (int kk = 0; kk < 32; kk += 2) {
        bf16x8 a0 = *(const bf16x8*)(hrd + ((kk * 64 + gq * 16) ^ swz_r));
        bf16x8 a1 = *(const bf16x8*)(hrd + (((kk + 1) * 64 + gq * 16) ^ swz_r));
        acc0 = __builtin_amdgcn_mfma_f32_16x16x32_bf16(a0, wf[kk], acc0, 0, 0, 0);
        acc1 = __builtin_amdgcn_mfma_f32_16x16x32_bf16(a1, wf[kk + 1], acc1, 0, 0, 0);
      }
      acc0 += acc1;
    } else {
      __syncthreads();
    }
    // gate exchange: wave (g,c4) tile -> C[row=gq*4+r][col=rl]
#pragma unroll
    for (int r = 0; r < 4; ++r)
      gate_lds[g][c4][gq * 4 + r][rl] = acc0[r];
    __syncthreads();
    // elementwise: thread owns (b_el, hcol)
    {
      const int cq = hcol >> 4, cl = hcol & 15;
      const float gi = gate_lds[0][cq][b_el][cl] + xg0;
      const float gf = gate_lds[1][cq][b_el][cl] + xg1;
      const float gg = gate_lds[2][cq][b_el][cl] + xg2;
      const float go = gate_lds[3][cq][b_el][cl] + xg3;
      const float iv = sigm(gi);
      const float fv = sigm(gf);
      const float gv = tanh_fast(gg);
      const float ov = sigm(go);
      creg = fv * creg + iv * gv;
      hreg = ov * tanh_fast(creg);
      // tagged h store FIRST (critical path), fire-and-forget
      const u32 wv = (u32)f2bf(hreg) | ((u32)(t + 1) << 16);
      __hip_atomic_store(
          &h_tag[(size_t)((t + 1) & 1) * 65536 + (size_t)(bg * 16 + b_el) * 1024 + cr * 64 + hcol],
          wv, __ATOMIC_RELAXED, __HIP_MEMORY_SCOPE_AGENT);
      // out store after (off the critical path)
      out[((size_t)t * BATCH + bg * 16 + b_el) * HDIM + cr * 64 + hcol] = hreg;
    }
    xg0 = bf2f(nx0); xg1 = bf2f(nx1); xg2 = bf2f(nx2); xg3 = bf2f(nx3);
    xp_p += XP_STEP;
  }
  // hT, cT
  out[(size_t)HS_ELEMS + (size_t)(bg * 16 + b_el) * HDIM + cr * 64 + hcol] = hreg;
  out[(size_t)HS_ELEMS + 65536u + (size_t)(bg * 16 + b_el) * HDIM + cr * 64 + hcol] = creg;
}

// ---------------------------------------------------------------------------
// Workspace layout (bytes):
//   [0,        524288)    h_tag: 2 slots x 64 x 1024 u32 (aliases WxT region)
//   [0,        8388608)   WxT (gemm only; dead before zero_tags runs)
//   [8388608,  16777216)  WhT [4096][1024] bf16
//   [16777216, +256MB)    Xp blocked [512][64][4][1024] u16
// ---------------------------------------------------------------------------
extern "C" void kernel_launch(void* const* d_in, const int* in_sizes, int n_in,
                              void* d_out, int out_size, void* d_ws, size_t ws_size,
                              hipStream_t stream) {
  const float* x = (const float*)d_in[0];
  const float* Wx = (const float*)d_in[1];
  const float* Wh = (const float*)d_in[2];
  const float* bias = (const float*)d_in[3];
  float* out = (float*)d_out;
  char* ws = (char*)d_ws;

  u16* WxT = (u16*)(ws + 0);
  u32* h_tag = (u32*)(ws + 0); // aliases WxT; live only after zero_tags
  u16* WhT = (u16*)(ws + 8388608);
  u16* Xp = (u16*)(ws + 16777216);

  transpose_w<<<dim3(128, 32, 2), dim3(32, 8), 0, stream>>>(Wx, Wh, WxT, WhT);
  gemm_xp<<<dim3(8192), dim3(256), 0, stream>>>(x, WxT, bias, Xp);
  zero_tags<<<dim3(512), dim3(256), 0, stream>>>(h_tag);
  lstm_rec<<<dim3(64), dim3(1024), 0, stream>>>(Xp, WhT, h_tag, out);
}

// Round 7
// 3691.855 us; speedup vs baseline: 2.2308x; 2.2308x over previous
//
#include <hip/hip_runtime.h>

typedef unsigned short u16;
typedef unsigned int u32;
typedef unsigned long long u64;
typedef float f32x4 __attribute__((ext_vector_type(4)));
typedef __bf16 bf16x8 __attribute__((ext_vector_type(8)));
typedef u16 u16x8 __attribute__((ext_vector_type(8)));

#define T_STEPS 512
#define BATCH 64
#define HDIM 1024
#define GDIM 4096            // 4*H
#define HS_ELEMS (33554432u) // 512*64*1024
#define XP_STEP 262144       // u16 per t: 128 blk * 4 gate * 512

__device__ __forceinline__ u16 f2bf(float f) {
  union { float f; u32 u; } v; v.f = f;
  u32 r = v.u + 0x7fffu + ((v.u >> 16) & 1u);
  return (u16)(r >> 16);
}
__device__ __forceinline__ float bf2f(u16 b) {
  union { u32 u; float f; } v; v.u = ((u32)b) << 16;
  return v.f;
}
__device__ __forceinline__ float sigm(float x) { return 1.f / (1.f + __expf(-x)); }
__device__ __forceinline__ float tanh_fast(float x) { return 1.f - 2.f / (__expf(2.f * x) + 1.f); }

// ---------------------------------------------------------------------------
// Kernel 1: transpose+convert W_x, W_h: [1024][4096] fp32 -> [4096][1024] bf16.
// ---------------------------------------------------------------------------
__global__ void transpose_w(const float* __restrict__ Wx, const float* __restrict__ Wh,
                            u16* __restrict__ WxT, u16* __restrict__ WhT) {
  __shared__ float tile[32][33];
  const float* src = blockIdx.z ? Wh : Wx;
  u16* dst = blockIdx.z ? WhT : WxT;
  const int n0 = blockIdx.x * 32, k0 = blockIdx.y * 32;
  const int tx = threadIdx.x, ty = threadIdx.y;
#pragma unroll
  for (int i = 0; i < 4; ++i)
    tile[ty + i * 8][tx] = src[(size_t)(k0 + ty + i * 8) * GDIM + n0 + tx];
  __syncthreads();
#pragma unroll
  for (int i = 0; i < 4; ++i)
    dst[(size_t)(n0 + ty + i * 8) * HDIM + k0 + tx] = f2bf(tile[tx][ty + i * 8]);
}

// ---------------------------------------------------------------------------
// Kernel 2: Xp = bf16(X @ W_x + b), blocked for the 128-block recurrence:
//   Xp[t][blk=bg*32+cr][gate][b_el*32+hcol]  (u16)
// ---------------------------------------------------------------------------
__global__ __launch_bounds__(256, 2) void gemm_xp(
    const float* __restrict__ X, const u16* __restrict__ WxT,
    const float* __restrict__ bias, u16* __restrict__ Xp) {
  __shared__ u16 As[128 * 40];
  __shared__ u16 Bs[128 * 40];
  const int tid = threadIdx.x;
  const int lane = tid & 63, w = tid >> 6;
  const int rl = lane & 15, gq = lane >> 4, g8 = gq * 8;
  const int swz = (blockIdx.x & 7) * 1024 + (blockIdx.x >> 3);
  const int m0 = (swz >> 5) * 128, n0 = (swz & 31) * 128;
  const int srow = tid >> 1, sseg = (tid & 1) * 16;
  const int rbase = (w >> 1) * 64, cbase = (w & 1) * 64;

  f32x4 acc[4][4] = {};
  for (int k0 = 0; k0 < 1024; k0 += 32) {
    const float4* ap = (const float4*)&X[(size_t)(m0 + srow) * 1024 + k0 + sseg];
    float4 v0 = ap[0], v1 = ap[1], v2 = ap[2], v3 = ap[3];
    u16x8 pa, pb;
    pa[0] = f2bf(v0.x); pa[1] = f2bf(v0.y); pa[2] = f2bf(v0.z); pa[3] = f2bf(v0.w);
    pa[4] = f2bf(v1.x); pa[5] = f2bf(v1.y); pa[6] = f2bf(v1.z); pa[7] = f2bf(v1.w);
    pb[0] = f2bf(v2.x); pb[1] = f2bf(v2.y); pb[2] = f2bf(v2.z); pb[3] = f2bf(v2.w);
    pb[4] = f2bf(v3.x); pb[5] = f2bf(v3.y); pb[6] = f2bf(v3.z); pb[7] = f2bf(v3.w);
    const u16x8* bp = (const u16x8*)&WxT[(size_t)(n0 + srow) * 1024 + k0 + sseg];
    u16x8 qa = bp[0], qb = bp[1];
    *(u16x8*)&As[srow * 40 + sseg] = pa;
    *(u16x8*)&As[srow * 40 + sseg + 8] = pb;
    *(u16x8*)&Bs[srow * 40 + sseg] = qa;
    *(u16x8*)&Bs[srow * 40 + sseg + 8] = qb;
    __syncthreads();
    bf16x8 av[4], bv[4];
#pragma unroll
    for (int i = 0; i < 4; ++i)
      av[i] = *(const bf16x8*)&As[(rbase + i * 16 + rl) * 40 + g8];
#pragma unroll
    for (int j = 0; j < 4; ++j)
      bv[j] = *(const bf16x8*)&Bs[(cbase + j * 16 + rl) * 40 + g8];
#pragma unroll
    for (int i = 0; i < 4; ++i)
#pragma unroll
      for (int j = 0; j < 4; ++j)
        acc[i][j] = __builtin_amdgcn_mfma_f32_16x16x32_bf16(av[i], bv[j], acc[i][j], 0, 0, 0);
    __syncthreads();
  }
#pragma unroll
  for (int j = 0; j < 4; ++j) {
    const int n = n0 + cbase + j * 16 + rl;
    const float bj = bias[n];
    const int gate = n >> 10, col = n & 1023;
    const int cri = col >> 5, hcoli = col & 31;
#pragma unroll
    for (int i = 0; i < 4; ++i)
#pragma unroll
      for (int r = 0; r < 4; ++r) {
        const int m = m0 + rbase + i * 16 + gq * 4 + r;
        const int tt = m >> 6, b = m & 63;
        Xp[(size_t)tt * XP_STEP + (size_t)((b >> 4) * 32 + cri) * 2048 +
           gate * 512 + (b & 15) * 32 + hcoli] = f2bf(acc[i][j][r] + bj);
      }
  }
}

// ---------------------------------------------------------------------------
// Kernel 3: zero h_tag (2 slots x 64 x 1024 u32 = 512KB), every launch
// (replay safety; h_tag aliases the dead WxT region).
// ---------------------------------------------------------------------------
__global__ void zero_tags(u32* __restrict__ ht) {
  ht[(size_t)blockIdx.x * 256 + threadIdx.x] = 0;
}

// ---------------------------------------------------------------------------
// Kernel 4: recurrence. Flagless tagged dataflow, 128 blocks x 512 threads.
// 128 blocks = 4 bg-groups x 32 col-ranges; only same-bg blocks communicate.
// Block (bg, cr) owns batches [bg*16..+16) x h-cols [cr*32..+32).
// 8 waves: wave w -> gate g=w>>1, col-half c2=w&1 -> one 16x16 output tile.
// wf[32] = 64 VGPRs/thread; 512 thr @ 2 waves/SIMD -> 256-VGPR cap (no spill;
// R6's 1024-thr/64-VGPR cliff was the regression).
// Per-thread poll width 16 u64 (vs 32 in R5 -> unpack VALU halved);
// aggregate h re-read 8 MB/step (vs 16 in R5).
// Protocol (proven R5): h word = (tag=t+1)<<16 | bf16; producers fire-and-
// forget relaxed agent stores; consumers poll tags in batched predicated
// rounds; 2-slot ping-pong safe by induction.
// ---------------------------------------------------------------------------
__global__ __launch_bounds__(512, 1) void lstm_rec(
    const u16* __restrict__ Xp, const u16* __restrict__ WhT,
    u32* __restrict__ h_tag, float* __restrict__ out) {
  __shared__ u16 h_lds[16 * 1024]; // [16 rows][1024 k] bf16, XOR-swizzled
  __shared__ float gate_lds[4][2][16][20];
  const int tid = threadIdx.x;
  const int lane = tid & 63, w = tid >> 6;
  const int rl = lane & 15, gq = lane >> 4;
  const int cr = blockIdx.x & 31, bg = blockIdx.x >> 5;
  const int g = w >> 1, c2 = w & 1;

  // W_h fragments (wave (g,c2): cols g*1024 + cr*32 + c2*16 + rl)
  bf16x8 wf[32];
  {
    const size_t gcol = (size_t)(g * 1024 + cr * 32 + c2 * 16 + rl) * HDIM + gq * 8;
#pragma unroll
    for (int kk = 0; kk < 32; ++kk)
      wf[kk] = *(const bf16x8*)&WhT[gcol + kk * 32];
  }

  // elementwise/store ownership: thread -> (b_el = tid>>5, hcol = tid&31)
  const int b_el = tid >> 5, hcol = tid & 31;
  // staging ownership: thread -> row srow = tid>>5, word-lane s32 = tid&31
  const int srow = tid >> 5, s32 = tid & 31;
  const int swz_w = ((srow & 7) << 4) ^ ((srow & 1) << 6);
  const int swz_r = ((rl & 7) << 4) ^ ((rl & 1) << 6);
  float creg = 0.f, hreg = 0.f;

  const u16* xp_p = Xp + (size_t)blockIdx.x * 2048 + tid;
  float xg0 = bf2f(xp_p[0]), xg1 = bf2f(xp_p[512]),
        xg2 = bf2f(xp_p[1024]), xg3 = bf2f(xp_p[1536]);

  for (int t = 0; t < T_STEPS; ++t) {
    // prefetch next step's Xp (independent of h; overlaps poll latency)
    u16 nx0 = 0, nx1 = 0, nx2 = 0, nx3 = 0;
    if (t + 1 < T_STEPS) {
      const u16* p = xp_p + XP_STEP;
      nx0 = p[0]; nx1 = p[512]; nx2 = p[1024]; nx3 = p[1536];
    }

    f32x4 acc0 = {0.f, 0.f, 0.f, 0.f}, acc1 = {0.f, 0.f, 0.f, 0.f};
    if (t > 0) {
      // batched tag-poll + stage: thread covers row srow, u64 words s32+32u
      const u64* hrow =
          (const u64*)(h_tag + (size_t)(t & 1) * 65536 + (size_t)(bg * 16 + srow) * 1024);
      char* ldsrow = (char*)h_lds + srow * 2048;
      u64 v[16];
      u32 pend = 0xffffu;
      while (pend) {
#pragma unroll
        for (int u = 0; u < 16; ++u)
          if (pend & (1u << u))
            v[u] = __hip_atomic_load(&hrow[s32 + 32 * u], __ATOMIC_RELAXED,
                                     __HIP_MEMORY_SCOPE_AGENT);
        u32 got = 0u;
#pragma unroll
        for (int u = 0; u < 16; ++u)
          if (pend & (1u << u)) {
            const u32 t0 = (u32)(v[u] >> 16) & 0xffffu, t1 = (u32)(v[u] >> 48);
            if (t0 >= (u32)t && t1 >= (u32)t) {
              const u32 pack = ((u32)v[u] & 0xffffu) | (((u32)(v[u] >> 32) & 0xffffu) << 16);
              *(u32*)(ldsrow + (((s32 + 32 * u) * 4) ^ swz_w)) = pack;
              got |= (1u << u);
            }
          }
        pend &= ~got;
      }
      __syncthreads();
      const char* hrd = (const char*)h_lds + rl * 2048;
#pragma unroll
      for (int kk = 0; kk < 32; kk += 2) {
        bf16x8 a0 = *(const bf16x8*)(hrd + ((kk * 64 + gq * 16) ^ swz_r));
        bf16x8 a1 = *(const bf16x8*)(hrd + (((kk + 1) * 64 + gq * 16) ^ swz_r));
        acc0 = __builtin_amdgcn_mfma_f32_16x16x32_bf16(a0, wf[kk], acc0, 0, 0, 0);
        acc1 = __builtin_amdgcn_mfma_f32_16x16x32_bf16(a1, wf[kk + 1], acc1, 0, 0, 0);
      }
      acc0 += acc1;
    } else {
      __syncthreads();
    }
    // gate exchange: wave (g,c2) tile -> C[row=gq*4+r][col=rl]
#pragma unroll
    for (int r = 0; r < 4; ++r)
      gate_lds[g][c2][gq * 4 + r][rl] = acc0[r];
    __syncthreads();
    // elementwise: thread owns (b_el, hcol)
    {
      const int cq = hcol >> 4, cl = hcol & 15;
      const float gi = gate_lds[0][cq][b_el][cl] + xg0;
      const float gf = gate_lds[1][cq][b_el][cl] + xg1;
      const float gg = gate_lds[2][cq][b_el][cl] + xg2;
      const float go = gate_lds[3][cq][b_el][cl] + xg3;
      const float iv = sigm(gi);
      const float fv = sigm(gf);
      const float gv = tanh_fast(gg);
      const float ov = sigm(go);
      creg = fv * creg + iv * gv;
      hreg = ov * tanh_fast(creg);
      // tagged h store FIRST (critical path), fire-and-forget
      const u32 wv = (u32)f2bf(hreg) | ((u32)(t + 1) << 16);
      __hip_atomic_store(
          &h_tag[(size_t)((t + 1) & 1) * 65536 + (size_t)(bg * 16 + b_el) * 1024 + cr * 32 + hcol],
          wv, __ATOMIC_RELAXED, __HIP_MEMORY_SCOPE_AGENT);
      // out store after (off the critical path)
      out[((size_t)t * BATCH + bg * 16 + b_el) * HDIM + cr * 32 + hcol] = hreg;
    }
    xg0 = bf2f(nx0); xg1 = bf2f(nx1); xg2 = bf2f(nx2); xg3 = bf2f(nx3);
    xp_p += XP_STEP;
  }
  // hT, cT
  out[(size_t)HS_ELEMS + (size_t)(bg * 16 + b_el) * HDIM + cr * 32 + hcol] = hreg;
  out[(size_t)HS_ELEMS + 65536u + (size_t)(bg * 16 + b_el) * HDIM + cr * 32 + hcol] = creg;
}

// ---------------------------------------------------------------------------
// Workspace layout (bytes):
//   [0,        524288)    h_tag: 2 slots x 64 x 1024 u32 (aliases WxT region)
//   [0,        8388608)   WxT (gemm only; dead before zero_tags runs)
//   [8388608,  16777216)  WhT [4096][1024] bf16
//   [16777216, +256MB)    Xp blocked [512][128][4][512] u16
// ---------------------------------------------------------------------------
extern "C" void kernel_launch(void* const* d_in, const int* in_sizes, int n_in,
                              void* d_out, int out_size, void* d_ws, size_t ws_size,
                              hipStream_t stream) {
  const float* x = (const float*)d_in[0];
  const float* Wx = (const float*)d_in[1];
  const float* Wh = (const float*)d_in[2];
  const float* bias = (const float*)d_in[3];
  float* out = (float*)d_out;
  char* ws = (char*)d_ws;

  u16* WxT = (u16*)(ws + 0);
  u32* h_tag = (u32*)(ws + 0); // aliases WxT; live only after zero_tags
  u16* WhT = (u16*)(ws + 8388608);
  u16* Xp = (u16*)(ws + 16777216);

  transpose_w<<<dim3(128, 32, 2), dim3(32, 8), 0, stream>>>(Wx, Wh, WxT, WhT);
  gemm_xp<<<dim3(8192), dim3(256), 0, stream>>>(x, WxT, bias, Xp);
  zero_tags<<<dim3(512), dim3(256), 0, stream>>>(h_tag);
  lstm_rec<<<dim3(128), dim3(512), 0, stream>>>(Xp, WhT, h_tag, out);
}

// Round 8
// 2588.041 us; speedup vs baseline: 3.1822x; 1.4265x over previous
//
#include <hip/hip_runtime.h>

typedef unsigned short u16;
typedef unsigned int u32;
typedef unsigned long long u64;
typedef float f32x4 __attribute__((ext_vector_type(4)));
typedef __bf16 bf16x8 __attribute__((ext_vector_type(8)));
typedef u16 u16x8 __attribute__((ext_vector_type(8)));

#define T_STEPS 512
#define BATCH 64
#define HDIM 1024
#define GDIM 4096            // 4*H
#define HS_ELEMS (33554432u) // 512*64*1024
#define XP_STEP 262144       // u16 per t: 128 blk * 4 gate * 512

__device__ __forceinline__ u16 f2bf(float f) {
  union { float f; u32 u; } v; v.f = f;
  u32 r = v.u + 0x7fffu + ((v.u >> 16) & 1u);
  return (u16)(r >> 16);
}
__device__ __forceinline__ float bf2f(u16 b) {
  union { u32 u; float f; } v; v.u = ((u32)b) << 16;
  return v.f;
}
__device__ __forceinline__ float sigm(float x) { return 1.f / (1.f + __expf(-x)); }
__device__ __forceinline__ float tanh_fast(float x) { return 1.f - 2.f / (__expf(2.f * x) + 1.f); }

// ---------------------------------------------------------------------------
// Kernel 1: transpose+convert W_x, W_h: [1024][4096] fp32 -> [4096][1024] bf16.
// ---------------------------------------------------------------------------
__global__ void transpose_w(const float* __restrict__ Wx, const float* __restrict__ Wh,
                            u16* __restrict__ WxT, u16* __restrict__ WhT) {
  __shared__ float tile[32][33];
  const float* src = blockIdx.z ? Wh : Wx;
  u16* dst = blockIdx.z ? WhT : WxT;
  const int n0 = blockIdx.x * 32, k0 = blockIdx.y * 32;
  const int tx = threadIdx.x, ty = threadIdx.y;
#pragma unroll
  for (int i = 0; i < 4; ++i)
    tile[ty + i * 8][tx] = src[(size_t)(k0 + ty + i * 8) * GDIM + n0 + tx];
  __syncthreads();
#pragma unroll
  for (int i = 0; i < 4; ++i)
    dst[(size_t)(n0 + ty + i * 8) * HDIM + k0 + tx] = f2bf(tile[tx][ty + i * 8]);
}

// ---------------------------------------------------------------------------
// Kernel 2: Xp = bf16(X @ W_x + b), blocked for the 128-block recurrence:
//   Xp[t][blk=bg*32+cr][gate][b_el*32+hcol]  (u16)   (unchanged from R7)
// ---------------------------------------------------------------------------
__global__ __launch_bounds__(256, 2) void gemm_xp(
    const float* __restrict__ X, const u16* __restrict__ WxT,
    const float* __restrict__ bias, u16* __restrict__ Xp) {
  __shared__ u16 As[128 * 40];
  __shared__ u16 Bs[128 * 40];
  const int tid = threadIdx.x;
  const int lane = tid & 63, w = tid >> 6;
  const int rl = lane & 15, gq = lane >> 4, g8 = gq * 8;
  const int swz = (blockIdx.x & 7) * 1024 + (blockIdx.x >> 3);
  const int m0 = (swz >> 5) * 128, n0 = (swz & 31) * 128;
  const int srow = tid >> 1, sseg = (tid & 1) * 16;
  const int rbase = (w >> 1) * 64, cbase = (w & 1) * 64;

  f32x4 acc[4][4] = {};
  for (int k0 = 0; k0 < 1024; k0 += 32) {
    const float4* ap = (const float4*)&X[(size_t)(m0 + srow) * 1024 + k0 + sseg];
    float4 v0 = ap[0], v1 = ap[1], v2 = ap[2], v3 = ap[3];
    u16x8 pa, pb;
    pa[0] = f2bf(v0.x); pa[1] = f2bf(v0.y); pa[2] = f2bf(v0.z); pa[3] = f2bf(v0.w);
    pa[4] = f2bf(v1.x); pa[5] = f2bf(v1.y); pa[6] = f2bf(v1.z); pa[7] = f2bf(v1.w);
    pb[0] = f2bf(v2.x); pb[1] = f2bf(v2.y); pb[2] = f2bf(v2.z); pb[3] = f2bf(v2.w);
    pb[4] = f2bf(v3.x); pb[5] = f2bf(v3.y); pb[6] = f2bf(v3.z); pb[7] = f2bf(v3.w);
    const u16x8* bp = (const u16x8*)&WxT[(size_t)(n0 + srow) * 1024 + k0 + sseg];
    u16x8 qa = bp[0], qb = bp[1];
    *(u16x8*)&As[srow * 40 + sseg] = pa;
    *(u16x8*)&As[srow * 40 + sseg + 8] = pb;
    *(u16x8*)&Bs[srow * 40 + sseg] = qa;
    *(u16x8*)&Bs[srow * 40 + sseg + 8] = qb;
    __syncthreads();
    bf16x8 av[4], bv[4];
#pragma unroll
    for (int i = 0; i < 4; ++i)
      av[i] = *(const bf16x8*)&As[(rbase + i * 16 + rl) * 40 + g8];
#pragma unroll
    for (int j = 0; j < 4; ++j)
      bv[j] = *(const bf16x8*)&Bs[(cbase + j * 16 + rl) * 40 + g8];
#pragma unroll
    for (int i = 0; i < 4; ++i)
#pragma unroll
      for (int j = 0; j < 4; ++j)
        acc[i][j] = __builtin_amdgcn_mfma_f32_16x16x32_bf16(av[i], bv[j], acc[i][j], 0, 0, 0);
    __syncthreads();
  }
#pragma unroll
  for (int j = 0; j < 4; ++j) {
    const int n = n0 + cbase + j * 16 + rl;
    const float bj = bias[n];
    const int gate = n >> 10, col = n & 1023;
    const int cri = col >> 5, hcoli = col & 31;
#pragma unroll
    for (int i = 0; i < 4; ++i)
#pragma unroll
      for (int r = 0; r < 4; ++r) {
        const int m = m0 + rbase + i * 16 + gq * 4 + r;
        const int tt = m >> 6, b = m & 63;
        Xp[(size_t)tt * XP_STEP + (size_t)((b >> 4) * 32 + cri) * 2048 +
           gate * 512 + (b & 15) * 32 + hcoli] = f2bf(acc[i][j][r] + bj);
      }
  }
}

// ---------------------------------------------------------------------------
// Kernel 3: zero h_tag (131072 u32) + flags (128 u32, contiguous after h_tag),
// every launch (replay safety; both alias the dead WxT region).
// ---------------------------------------------------------------------------
__global__ void zero_tags(u32* __restrict__ ht) {
  const u32 i = blockIdx.x * 256 + threadIdx.x;
  if (i < 131200u) ht[i] = 0;
}

// ---------------------------------------------------------------------------
// Kernel 4: recurrence. Tagged dataflow + fire-and-forget flags.
// 128 blocks = 4 bg-groups x 32 col-ranges; only same-bg blocks communicate.
// Block (bg, cr) owns batches [bg*16..+16) x h-cols [cr*32..+32).
// Producer per step: tagged h stores (u32 = (t+1)<<16 | bf16), then tid==0
//   stores flags[bg*32+cr] = t+1 with NO vmcnt/sync (fabric races caught by
//   per-word tags). Out stores after (off critical path).
// Consumer: tight flag spin (1 load/lane + __all per iter, ~1 RT granularity)
//   -> ONE bulk pass of 16 u64/thread -> unpack -> swizzled LDS; per-word
//   tag check routes rare stragglers to a refetch loop.
// Slot safety: unchanged 2-slot induction (flag t+1 implies producer consumed
//   h(t), which implies every block finished slot (t+1)&1's previous tag).
// ---------------------------------------------------------------------------
__global__ __launch_bounds__(512, 1) void lstm_rec(
    const u16* __restrict__ Xp, const u16* __restrict__ WhT,
    u32* __restrict__ h_tag, u32* __restrict__ flags, float* __restrict__ out) {
  __shared__ u16 h_lds[16 * 1024]; // [16 rows][1024 k] bf16, XOR-swizzled
  __shared__ float gate_lds[4][2][16][20];
  const int tid = threadIdx.x;
  const int lane = tid & 63, w = tid >> 6;
  const int rl = lane & 15, gq = lane >> 4;
  const int cr = blockIdx.x & 31, bg = blockIdx.x >> 5;
  const int g = w >> 1, c2 = w & 1;

  // W_h fragments (wave (g,c2): cols g*1024 + cr*32 + c2*16 + rl)
  bf16x8 wf[32];
  {
    const size_t gcol = (size_t)(g * 1024 + cr * 32 + c2 * 16 + rl) * HDIM + gq * 8;
#pragma unroll
    for (int kk = 0; kk < 32; ++kk)
      wf[kk] = *(const bf16x8*)&WhT[gcol + kk * 32];
  }

  // elementwise/store ownership: thread -> (b_el = tid>>5, hcol = tid&31)
  const int b_el = tid >> 5, hcol = tid & 31;
  // staging ownership: thread -> row srow = tid>>5, word-lane s32 = tid&31
  const int srow = tid >> 5, s32 = tid & 31;
  const int swz_w = ((srow & 7) << 4) ^ ((srow & 1) << 6);
  const int swz_r = ((rl & 7) << 4) ^ ((rl & 1) << 6);
  float creg = 0.f, hreg = 0.f;

  const u16* xp_p = Xp + (size_t)blockIdx.x * 2048 + tid;
  float xg0 = bf2f(xp_p[0]), xg1 = bf2f(xp_p[512]),
        xg2 = bf2f(xp_p[1024]), xg3 = bf2f(xp_p[1536]);

  const u32* flagrow = flags + bg * 32 + (lane & 31); // each flag spun by 2 lanes

  for (int t = 0; t < T_STEPS; ++t) {
    // prefetch next step's Xp (independent of h; overlaps spin latency)
    u16 nx0 = 0, nx1 = 0, nx2 = 0, nx3 = 0;
    if (t + 1 < T_STEPS) {
      const u16* p = xp_p + XP_STEP;
      nx0 = p[0]; nx1 = p[512]; nx2 = p[1024]; nx3 = p[1536];
    }

    f32x4 acc0 = {0.f, 0.f, 0.f, 0.f}, acc1 = {0.f, 0.f, 0.f, 0.f};
    if (t > 0) {
      // ---- 1) cheap detect: 1 flag load per lane per spin iter ----
      for (;;) {
        u32 f = __hip_atomic_load(flagrow, __ATOMIC_RELAXED, __HIP_MEMORY_SCOPE_AGENT);
        if (__all((int)(f >= (u32)t))) break;
      }
      // ---- 2) single bulk pass: 16 u64/thread, tag-verified ----
      const u64* hrow =
          (const u64*)(h_tag + (size_t)(t & 1) * 65536 + (size_t)(bg * 16 + srow) * 1024);
      char* ldsrow = (char*)h_lds + srow * 2048;
      u64 v[16];
#pragma unroll
      for (int u = 0; u < 16; ++u)
        v[u] = __hip_atomic_load(&hrow[s32 + 32 * u], __ATOMIC_RELAXED,
                                 __HIP_MEMORY_SCOPE_AGENT);
      u32 pend = 0u;
#pragma unroll
      for (int u = 0; u < 16; ++u) {
        const u32 t0 = (u32)(v[u] >> 16) & 0xffffu, t1 = (u32)(v[u] >> 48);
        const u32 pack = ((u32)v[u] & 0xffffu) | (((u32)(v[u] >> 32) & 0xffffu) << 16);
        *(u32*)(ldsrow + (((s32 + 32 * u) * 4) ^ swz_w)) = pack;
        if (t0 < (u32)t || t1 < (u32)t) pend |= (1u << u);
      }
      // rare straggler path (flag/data raced in the fabric)
      while (__builtin_expect(pend != 0u, 0)) {
        const int uu = __ffs(pend) - 1;
        u64 vv = __hip_atomic_load(&hrow[s32 + 32 * uu], __ATOMIC_RELAXED,
                                   __HIP_MEMORY_SCOPE_AGENT);
        const u32 t0 = (u32)(vv >> 16) & 0xffffu, t1 = (u32)(vv >> 48);
        if (t0 >= (u32)t && t1 >= (u32)t) {
          const u32 pack = ((u32)vv & 0xffffu) | (((u32)(vv >> 32) & 0xffffu) << 16);
          *(u32*)(ldsrow + (((s32 + 32 * uu) * 4) ^ swz_w)) = pack;
          pend &= pend - 1u;
        }
      }
      __syncthreads();
      const char* hrd = (const char*)h_lds + rl * 2048;
#pragma unroll
      for (int kk = 0; kk < 32; kk += 2) {
        bf16x8 a0 = *(const bf16x8*)(hrd + ((kk * 64 + gq * 16) ^ swz_r));
        bf16x8 a1 = *(const bf16x8*)(hrd + (((kk + 1) * 64 + gq * 16) ^ swz_r));
        acc0 = __builtin_amdgcn_mfma_f32_16x16x32_bf16(a0, wf[kk], acc0, 0, 0, 0);
        acc1 = __builtin_amdgcn_mfma_f32_16x16x32_bf16(a1, wf[kk + 1], acc1, 0, 0, 0);
      }
      acc0 += acc1;
    } else {
      __syncthreads();
    }
    // gate exchange: wave (g,c2) tile -> C[row=gq*4+r][col=rl]
#pragma unroll
    for (int r = 0; r < 4; ++r)
      gate_lds[g][c2][gq * 4 + r][rl] = acc0[r];
    __syncthreads();
    // elementwise: thread owns (b_el, hcol)
    {
      const int cq = hcol >> 4, cl = hcol & 15;
      const float gi = gate_lds[0][cq][b_el][cl] + xg0;
      const float gf = gate_lds[1][cq][b_el][cl] + xg1;
      const float gg = gate_lds[2][cq][b_el][cl] + xg2;
      const float go = gate_lds[3][cq][b_el][cl] + xg3;
      const float iv = sigm(gi);
      const float fv = sigm(gf);
      const float gv = tanh_fast(gg);
      const float ov = sigm(go);
      creg = fv * creg + iv * gv;
      hreg = ov * tanh_fast(creg);
      // tagged h store FIRST (critical path), fire-and-forget
      const u32 wv = (u32)f2bf(hreg) | ((u32)(t + 1) << 16);
      __hip_atomic_store(
          &h_tag[(size_t)((t + 1) & 1) * 65536 + (size_t)(bg * 16 + b_el) * 1024 + cr * 32 + hcol],
          wv, __ATOMIC_RELAXED, __HIP_MEMORY_SCOPE_AGENT);
    }
    // readiness flag: immediately after h stores, no ordering ops (tags are
    // the safety net). One store per block.
    if (tid == 0)
      __hip_atomic_store(&flags[bg * 32 + cr], (u32)(t + 1), __ATOMIC_RELAXED,
                         __HIP_MEMORY_SCOPE_AGENT);
    // out store after (off the critical path)
    out[((size_t)t * BATCH + bg * 16 + b_el) * HDIM + cr * 32 + hcol] = hreg;
    xg0 = bf2f(nx0); xg1 = bf2f(nx1); xg2 = bf2f(nx2); xg3 = bf2f(nx3);
    xp_p += XP_STEP;
  }
  // hT, cT
  out[(size_t)HS_ELEMS + (size_t)(bg * 16 + b_el) * HDIM + cr * 32 + hcol] = hreg;
  out[(size_t)HS_ELEMS + 65536u + (size_t)(bg * 16 + b_el) * HDIM + cr * 32 + hcol] = creg;
}

// ---------------------------------------------------------------------------
// Workspace layout (bytes):
//   [0,        524288)    h_tag: 2 slots x 64 x 1024 u32 (aliases WxT region)
//   [524288,   524800)    flags: 128 u32 (contiguous after h_tag)
//   [0,        8388608)   WxT (gemm only; dead before zero_tags runs)
//   [8388608,  16777216)  WhT [4096][1024] bf16
//   [16777216, +256MB)    Xp blocked [512][128][4][512] u16
// ---------------------------------------------------------------------------
extern "C" void kernel_launch(void* const* d_in, const int* in_sizes, int n_in,
                              void* d_out, int out_size, void* d_ws, size_t ws_size,
                              hipStream_t stream) {
  const float* x = (const float*)d_in[0];
  const float* Wx = (const float*)d_in[1];
  const float* Wh = (const float*)d_in[2];
  const float* bias = (const float*)d_in[3];
  float* out = (float*)d_out;
  char* ws = (char*)d_ws;

  u16* WxT = (u16*)(ws + 0);
  u32* h_tag = (u32*)(ws + 0);      // aliases WxT; live only after zero_tags
  u32* flags = (u32*)(ws + 524288); // ditto
  u16* WhT = (u16*)(ws + 8388608);
  u16* Xp = (u16*)(ws + 16777216);

  transpose_w<<<dim3(128, 32, 2), dim3(32, 8), 0, stream>>>(Wx, Wh, WxT, WhT);
  gemm_xp<<<dim3(8192), dim3(256), 0, stream>>>(x, WxT, bias, Xp);
  zero_tags<<<dim3(514), dim3(256), 0, stream>>>(h_tag);
  lstm_rec<<<dim3(128), dim3(512), 0, stream>>>(Xp, WhT, h_tag, flags, out);
}

// Round 9
// 2267.343 us; speedup vs baseline: 3.6323x; 1.1414x over previous
//
#include <hip/hip_runtime.h>

typedef unsigned short u16;
typedef unsigned int u32;
typedef unsigned long long u64;
typedef float f32x4 __attribute__((ext_vector_type(4)));
typedef __bf16 bf16x8 __attribute__((ext_vector_type(8)));
typedef u16 u16x8 __attribute__((ext_vector_type(8)));
typedef u32 u32x4 __attribute__((ext_vector_type(4)));

#define T_STEPS 512
#define BATCH 64
#define HDIM 1024
#define GDIM 4096            // 4*H
#define HS_ELEMS (33554432u) // 512*64*1024
#define XP_STEP 262144       // u16 per t: 128 blk * 4 gate * 512

__device__ __forceinline__ u16 f2bf(float f) {
  union { float f; u32 u; } v; v.f = f;
  u32 r = v.u + 0x7fffu + ((v.u >> 16) & 1u);
  return (u16)(r >> 16);
}
__device__ __forceinline__ float bf2f(u16 b) {
  union { u32 u; float f; } v; v.u = ((u32)b) << 16;
  return v.f;
}
__device__ __forceinline__ float sigm(float x) { return 1.f / (1.f + __expf(-x)); }
__device__ __forceinline__ float tanh_fast(float x) { return 1.f - 2.f / (__expf(2.f * x) + 1.f); }

// async global->LDS, 16B per lane; LDS dest = wave-uniform base + lane*16
__device__ __forceinline__ void gload16(const void* g, void* l) {
  __builtin_amdgcn_global_load_lds(
      (const __attribute__((address_space(1))) u32*)g,
      (__attribute__((address_space(3))) u32*)l, 16, 0, 0);
}
// coherent (L1/L2-bypassing) 16B load, fire-and-wait-later
__device__ __forceinline__ u32x4 cload16(const void* g) {
  u32x4 r;
  asm volatile("global_load_dwordx4 %0, %1, off sc0 sc1" : "=&v"(r) : "v"(g) : "memory");
  return r;
}

// ---------------------------------------------------------------------------
// Kernel 1: transpose+convert W_x, W_h: [1024][4096] fp32 -> [4096][1024] bf16.
// ---------------------------------------------------------------------------
__global__ void transpose_w(const float* __restrict__ Wx, const float* __restrict__ Wh,
                            u16* __restrict__ WxT, u16* __restrict__ WhT) {
  __shared__ float tile[32][33];
  const float* src = blockIdx.z ? Wh : Wx;
  u16* dst = blockIdx.z ? WhT : WxT;
  const int n0 = blockIdx.x * 32, k0 = blockIdx.y * 32;
  const int tx = threadIdx.x, ty = threadIdx.y;
#pragma unroll
  for (int i = 0; i < 4; ++i)
    tile[ty + i * 8][tx] = src[(size_t)(k0 + ty + i * 8) * GDIM + n0 + tx];
  __syncthreads();
#pragma unroll
  for (int i = 0; i < 4; ++i)
    dst[(size_t)(n0 + ty + i * 8) * HDIM + k0 + tx] = f2bf(tile[tx][ty + i * 8]);
}

// ---------------------------------------------------------------------------
// Kernel 1b: convert X fp32 -> bf16 (row layout preserved), into d_out scratch.
// 16384 blocks x 256 thr x 8 elems = 33,554,432 exactly.
// ---------------------------------------------------------------------------
__global__ void convert_x(const float* __restrict__ X, u16* __restrict__ Xbf) {
  const size_t i = ((size_t)blockIdx.x * 256 + threadIdx.x) * 8;
  const float4 a = *(const float4*)&X[i];
  const float4 b = *(const float4*)&X[i + 4];
  u16x8 o;
  o[0] = f2bf(a.x); o[1] = f2bf(a.y); o[2] = f2bf(a.z); o[3] = f2bf(a.w);
  o[4] = f2bf(b.x); o[5] = f2bf(b.y); o[6] = f2bf(b.z); o[7] = f2bf(b.w);
  *(u16x8*)&Xbf[i] = o;
}

// ---------------------------------------------------------------------------
// Kernel 2: Xp = bf16(Xbf @ W_x + b), m97-style structure:
// 128x128 tile, BK=32, both operands staged via global_load_lds (16B),
// linear LDS [128][32] bf16, 2-barrier K-loop, blocked-layout epilogue
// (Xp[t][blk=bg*32+cr][gate][b_el*32+hcol], unchanged from R8).
// ---------------------------------------------------------------------------
__global__ __launch_bounds__(256) void gemm_xp(
    const u16* __restrict__ Xbf, const u16* __restrict__ WxT,
    const float* __restrict__ bias, u16* __restrict__ Xp) {
  __shared__ u16 As[128 * 32];
  __shared__ u16 Bs[128 * 32];
  const int tid = threadIdx.x;
  const int lane = tid & 63, w = tid >> 6;
  const int rl = lane & 15, gq = lane >> 4, g8 = gq * 8;
  const int swz = (blockIdx.x & 7) * 1024 + (blockIdx.x >> 3);
  const int m0 = (swz >> 5) * 128, n0 = (swz & 31) * 128;
  const int rbase = (w >> 1) * 64, cbase = (w & 1) * 64;
  // staging: issue i covers rows r0 + i*64, cols c0..c0+8 (16B per lane)
  const int r0 = tid >> 2, c0 = (tid & 3) * 8;

  f32x4 acc[4][4] = {};
  for (int k0 = 0; k0 < 1024; k0 += 32) {
    gload16(&Xbf[(size_t)(m0 + r0) * 1024 + k0 + c0], &As[w * 512]);
    gload16(&Xbf[(size_t)(m0 + r0 + 64) * 1024 + k0 + c0], &As[2048 + w * 512]);
    gload16(&WxT[(size_t)(n0 + r0) * 1024 + k0 + c0], &Bs[w * 512]);
    gload16(&WxT[(size_t)(n0 + r0 + 64) * 1024 + k0 + c0], &Bs[2048 + w * 512]);
    __syncthreads(); // drains vmcnt (gload_lds) before ds_read
    bf16x8 av[4], bv[4];
#pragma unroll
    for (int i = 0; i < 4; ++i)
      av[i] = *(const bf16x8*)&As[(rbase + i * 16 + rl) * 32 + g8];
#pragma unroll
    for (int j = 0; j < 4; ++j)
      bv[j] = *(const bf16x8*)&Bs[(cbase + j * 16 + rl) * 32 + g8];
#pragma unroll
    for (int i = 0; i < 4; ++i)
#pragma unroll
      for (int j = 0; j < 4; ++j)
        acc[i][j] = __builtin_amdgcn_mfma_f32_16x16x32_bf16(av[i], bv[j], acc[i][j], 0, 0, 0);
    __syncthreads();
  }
#pragma unroll
  for (int j = 0; j < 4; ++j) {
    const int n = n0 + cbase + j * 16 + rl;
    const float bj = bias[n];
    const int gate = n >> 10, col = n & 1023;
    const int cri = col >> 5, hcoli = col & 31;
#pragma unroll
    for (int i = 0; i < 4; ++i)
#pragma unroll
      for (int r = 0; r < 4; ++r) {
        const int m = m0 + rbase + i * 16 + gq * 4 + r;
        const int tt = m >> 6, b = m & 63;
        Xp[(size_t)tt * XP_STEP + (size_t)((b >> 4) * 32 + cri) * 2048 +
           gate * 512 + (b & 15) * 32 + hcoli] = f2bf(acc[i][j][r] + bj);
      }
  }
}

// ---------------------------------------------------------------------------
// Kernel 3: zero h_tag (131072 u32) + flags (128 u32), every launch.
// ---------------------------------------------------------------------------
__global__ void zero_tags(u32* __restrict__ ht) {
  const u32 i = blockIdx.x * 256 + threadIdx.x;
  if (i < 131200u) ht[i] = 0;
}

// ---------------------------------------------------------------------------
// Kernel 4: recurrence (R8 protocol). Tagged dataflow + fire-and-forget flags.
// Change vs R8: bulk pass uses 8 x 16B coherent asm loads per thread (sc0 sc1,
// explicit vmcnt(0) + sched_barrier(0) before consuming) instead of 16 x 8B
// atomic loads; per-u32 tag checks; straggler refetch keeps atomic u64 path.
// ---------------------------------------------------------------------------
__global__ __launch_bounds__(512, 1) void lstm_rec(
    const u16* __restrict__ Xp, const u16* __restrict__ WhT,
    u32* __restrict__ h_tag, u32* __restrict__ flags, float* __restrict__ out) {
  __shared__ u16 h_lds[16 * 1024]; // [16 rows][1024 k] bf16, XOR-swizzled
  __shared__ float gate_lds[4][2][16][20];
  const int tid = threadIdx.x;
  const int lane = tid & 63, w = tid >> 6;
  const int rl = lane & 15, gq = lane >> 4;
  const int cr = blockIdx.x & 31, bg = blockIdx.x >> 5;
  const int g = w >> 1, c2 = w & 1;

  // W_h fragments (wave (g,c2): cols g*1024 + cr*32 + c2*16 + rl)
  bf16x8 wf[32];
  {
    const size_t gcol = (size_t)(g * 1024 + cr * 32 + c2 * 16 + rl) * HDIM + gq * 8;
#pragma unroll
    for (int kk = 0; kk < 32; ++kk)
      wf[kk] = *(const bf16x8*)&WhT[gcol + kk * 32];
  }

  const int b_el = tid >> 5, hcol = tid & 31;
  const int srow = tid >> 5, s32 = tid & 31;
  const int swz_w = ((srow & 7) << 4) ^ ((srow & 1) << 6);
  const int swz_r = ((rl & 7) << 4) ^ ((rl & 1) << 6);
  float creg = 0.f, hreg = 0.f;

  const u16* xp_p = Xp + (size_t)blockIdx.x * 2048 + tid;
  float xg0 = bf2f(xp_p[0]), xg1 = bf2f(xp_p[512]),
        xg2 = bf2f(xp_p[1024]), xg3 = bf2f(xp_p[1536]);

  const u32* flagrow = flags + bg * 32 + (lane & 31);

  for (int t = 0; t < T_STEPS; ++t) {
    // prefetch next step's Xp (independent of h; overlaps spin latency)
    u16 nx0 = 0, nx1 = 0, nx2 = 0, nx3 = 0;
    if (t + 1 < T_STEPS) {
      const u16* p = xp_p + XP_STEP;
      nx0 = p[0]; nx1 = p[512]; nx2 = p[1024]; nx3 = p[1536];
    }

    f32x4 acc0 = {0.f, 0.f, 0.f, 0.f}, acc1 = {0.f, 0.f, 0.f, 0.f};
    if (t > 0) {
      // ---- 1) cheap detect: 1 flag load per lane per spin iter ----
      for (;;) {
        u32 f = __hip_atomic_load(flagrow, __ATOMIC_RELAXED, __HIP_MEMORY_SCOPE_AGENT);
        if (__all((int)(f >= (u32)t))) break;
      }
      // ---- 2) single bulk pass: 8 x 16B coherent loads, tag-verified ----
      const u32* hrow32 =
          h_tag + (size_t)(t & 1) * 65536 + (size_t)(bg * 16 + srow) * 1024;
      char* ldsrow = (char*)h_lds + srow * 2048;
      u32x4 v[8];
#pragma unroll
      for (int u = 0; u < 8; ++u)
        v[u] = cload16((const char*)hrow32 + 512 * u + 16 * s32);
      asm volatile("s_waitcnt vmcnt(0)" ::: "memory");
      __builtin_amdgcn_sched_barrier(0);
      u32 pend = 0u;
#pragma unroll
      for (int u = 0; u < 8; ++u) {
        const u32 w0 = v[u][0], w1 = v[u][1], w2 = v[u][2], w3 = v[u][3];
        const u64 packs = (u64)((w0 & 0xffffu) | (w1 << 16)) |
                          ((u64)((w2 & 0xffffu) | (w3 << 16)) << 32);
        *(u64*)(ldsrow + ((256 * u + 8 * s32) ^ swz_w)) = packs;
        if ((w0 >> 16) < (u32)t || (w1 >> 16) < (u32)t ||
            (w2 >> 16) < (u32)t || (w3 >> 16) < (u32)t)
          pend |= (1u << u);
      }
      // rare straggler path (flag/data raced in the fabric): atomic u64 pairs
      while (__builtin_expect(pend != 0u, 0)) {
        const int uu = __ffs(pend) - 1;
        const u64* h64 = (const u64*)hrow32;
        const int j0 = 64 * uu + 2 * s32;
        u64 a = __hip_atomic_load(&h64[j0], __ATOMIC_RELAXED, __HIP_MEMORY_SCOPE_AGENT);
        u64 b = __hip_atomic_load(&h64[j0 + 1], __ATOMIC_RELAXED, __HIP_MEMORY_SCOPE_AGENT);
        const u32 t0 = (u32)(a >> 16) & 0xffffu, t1 = (u32)(a >> 48);
        const u32 t2 = (u32)(b >> 16) & 0xffffu, t3 = (u32)(b >> 48);
        if (t0 >= (u32)t && t1 >= (u32)t && t2 >= (u32)t && t3 >= (u32)t) {
          const u64 packs =
              (u64)(((u32)a & 0xffffu) | (((u32)(a >> 32) & 0xffffu) << 16)) |
              ((u64)(((u32)b & 0xffffu) | (((u32)(b >> 32) & 0xffffu) << 16)) << 32);
          *(u64*)(ldsrow + ((256 * uu + 8 * s32) ^ swz_w)) = packs;
          pend &= pend - 1u;
        }
      }
      __syncthreads();
      const char* hrd = (const char*)h_lds + rl * 2048;
#pragma unroll
      for (int kk = 0; kk < 32; kk += 2) {
        bf16x8 a0 = *(const bf16x8*)(hrd + ((kk * 64 + gq * 16) ^ swz_r));
        bf16x8 a1 = *(const bf16x8*)(hrd + (((kk + 1) * 64 + gq * 16) ^ swz_r));
        acc0 = __builtin_amdgcn_mfma_f32_16x16x32_bf16(a0, wf[kk], acc0, 0, 0, 0);
        acc1 = __builtin_amdgcn_mfma_f32_16x16x32_bf16(a1, wf[kk + 1], acc1, 0, 0, 0);
      }
      acc0 += acc1;
    } else {
      __syncthreads();
    }
    // gate exchange: wave (g,c2) tile -> C[row=gq*4+r][col=rl]
#pragma unroll
    for (int r = 0; r < 4; ++r)
      gate_lds[g][c2][gq * 4 + r][rl] = acc0[r];
    __syncthreads();
    // elementwise: thread owns (b_el, hcol)
    {
      const int cq = hcol >> 4, cl = hcol & 15;
      const float gi = gate_lds[0][cq][b_el][cl] + xg0;
      const float gf = gate_lds[1][cq][b_el][cl] + xg1;
      const float gg = gate_lds[2][cq][b_el][cl] + xg2;
      const float go = gate_lds[3][cq][b_el][cl] + xg3;
      const float iv = sigm(gi);
      const float fv = sigm(gf);
      const float gv = tanh_fast(gg);
      const float ov = sigm(go);
      creg = fv * creg + iv * gv;
      hreg = ov * tanh_fast(creg);
      // tagged h store FIRST (critical path), fire-and-forget
      const u32 wv = (u32)f2bf(hreg) | ((u32)(t + 1) << 16);
      __hip_atomic_store(
          &h_tag[(size_t)((t + 1) & 1) * 65536 + (size_t)(bg * 16 + b_el) * 1024 + cr * 32 + hcol],
          wv, __ATOMIC_RELAXED, __HIP_MEMORY_SCOPE_AGENT);
    }
    // readiness flag: immediately after h stores, no ordering ops (tags are
    // the safety net). One store per block.
    if (tid == 0)
      __hip_atomic_store(&flags[bg * 32 + cr], (u32)(t + 1), __ATOMIC_RELAXED,
                         __HIP_MEMORY_SCOPE_AGENT);
    // out store after (off the critical path)
    out[((size_t)t * BATCH + bg * 16 + b_el) * HDIM + cr * 32 + hcol] = hreg;
    xg0 = bf2f(nx0); xg1 = bf2f(nx1); xg2 = bf2f(nx2); xg3 = bf2f(nx3);
    xp_p += XP_STEP;
  }
  // hT, cT
  out[(size_t)HS_ELEMS + (size_t)(bg * 16 + b_el) * HDIM + cr * 32 + hcol] = hreg;
  out[(size_t)HS_ELEMS + 65536u + (size_t)(bg * 16 + b_el) * HDIM + cr * 32 + hcol] = creg;
}

// ---------------------------------------------------------------------------
// Workspace layout (bytes):
//   [0,        524288)    h_tag: 2 slots x 64 x 1024 u32 (aliases WxT region)
//   [524288,   524800)    flags: 128 u32
//   [0,        8388608)   WxT (gemm only; dead before zero_tags runs)
//   [8388608,  16777216)  WhT [4096][1024] bf16
//   [16777216, +256MB)    Xp blocked [512][128][4][512] u16
// Xbf (32768x1024 bf16, 64MB) lives in d_out[0..64MB): written by convert_x,
// read by gemm_xp, then fully overwritten by lstm_rec's out stores (stream-
// ordered within each launch; deterministic across replays).
// ---------------------------------------------------------------------------
extern "C" void kernel_launch(void* const* d_in, const int* in_sizes, int n_in,
                              void* d_out, int out_size, void* d_ws, size_t ws_size,
                              hipStream_t stream) {
  const float* x = (const float*)d_in[0];
  const float* Wx = (const float*)d_in[1];
  const float* Wh = (const float*)d_in[2];
  const float* bias = (const float*)d_in[3];
  float* out = (float*)d_out;
  char* ws = (char*)d_ws;

  u16* WxT = (u16*)(ws + 0);
  u32* h_tag = (u32*)(ws + 0);      // aliases WxT; live only after zero_tags
  u32* flags = (u32*)(ws + 524288); // ditto
  u16* WhT = (u16*)(ws + 8388608);
  u16* Xp = (u16*)(ws + 16777216);
  u16* Xbf = (u16*)d_out; // scratch in d_out, dead after gemm_xp

  transpose_w<<<dim3(128, 32, 2), dim3(32, 8), 0, stream>>>(Wx, Wh, WxT, WhT);
  convert_x<<<dim3(16384), dim3(256), 0, stream>>>(x, Xbf);
  gemm_xp<<<dim3(8192), dim3(256), 0, stream>>>(Xbf, WxT, bias, Xp);
  zero_tags<<<dim3(514), dim3(256), 0, stream>>>(h_tag);
  lstm_rec<<<dim3(128), dim3(512), 0, stream>>>(Xp, WhT, h_tag, flags, out);
}